// Round 1
// 451.142 us; speedup vs baseline: 1.0323x; 1.0323x over previous
//
#include <hip/hip_runtime.h>
#include <hip/hip_bf16.h>
#include <math.h>

#define MDIM 250
#define NDIM 250
#define DTOT 500          // M + N
#define HDIM 512
#define BATCH 1024
#define N_ITER 1000
#define OMEGA_C 1.8f
#define SIGMA_C 0.1f
#define EXIT_BOUND 0.08f  // guaranteed remaining movement; 0.08 + ~0.005 << 0.129

__device__ __forceinline__ float rlane(float v, int lane) {
    return __int_as_float(__builtin_amdgcn_readlane(__float_as_int(v), lane));
}

// ---------------------------------------------------------------------------
// Phase A — R10 rewrite: tiled GEMMs (16 rows x 64 cols / block, K-chunks of
// 64 staged in LDS). Old per-row MLP kernels had zero W reuse per block
// (~1 GB L2 traffic per layer ≈ 30+ us each); tiles give 16x reuse.
// ---------------------------------------------------------------------------

// At[k*250 + m] = Aaug[m*500 + k]  for k,m < 250
__global__ void at_kernel(const float* __restrict__ Aaug, float* __restrict__ At) {
    int o = blockIdx.x * blockDim.x + threadIdx.x;
    if (o >= MDIM * MDIM) return;
    int k = o / MDIM;
    int m = o % MDIM;
    At[o] = Aaug[m * DTOT + k];
}

// Y[1024,HOUT] = act(X[1024,K] @ W[K,HOUT] + bias)
// CONCAT: X row = [Xa_row(250) | Xb_row(250)] (row stride 250 each, scalar
// loads because 250 floats breaks float4 alignment on odd rows).
// Block: 256 threads; thread (cq=t&15, rr=t>>4) owns rows r0+rr, cols
// h0+4cq..h0+4cq+3. Per k: 1 broadcast ds_read_b32 + 1 ds_read_b128 + 4 fmac.
template<int K, int HOUT, bool RELU, bool CONCAT>
__global__ __launch_bounds__(256) void gemm_kernel(const float* __restrict__ Xa,
                                                   const float* __restrict__ Xb,
                                                   const float* __restrict__ W,
                                                   const float* __restrict__ bias,
                                                   float* __restrict__ Y) {
    __shared__ float Xs[16 * 68];   // Xs[r][k], pad 68 keeps b128 alignment + banks spread
    __shared__ float Ws[64 * 64];   // Ws[k][c]
    const int t  = threadIdx.x;
    const int cq = t & 15;          // col quad 0..15
    const int rr = t >> 4;          // row 0..15
    const int r0 = blockIdx.x * 16;
    const int h0 = blockIdx.y * 64;
    float acc[4] = {0.f, 0.f, 0.f, 0.f};

    for (int kk = 0; kk < K; kk += 64) {
        const int kc = (K - kk < 64) ? (K - kk) : 64;

        // ---- stage X tile: thread loads 4 k's of its own row ----
        {
            const int k4  = 4 * cq;
            const int row = r0 + rr;
            float4 xv = make_float4(0.f, 0.f, 0.f, 0.f);
            if (k4 < kc) {                        // kc is always a multiple of 4
                if (CONCAT) {
                    float tmp[4];
                    #pragma unroll
                    for (int i = 0; i < 4; ++i) {
                        int kg = kk + k4 + i;
                        tmp[i] = (kg < MDIM) ? Xa[row * MDIM + kg]
                                             : Xb[row * NDIM + (kg - MDIM)];
                    }
                    xv = make_float4(tmp[0], tmp[1], tmp[2], tmp[3]);
                } else {
                    xv = *(const float4*)(Xa + (size_t)row * K + kk + k4);
                }
            }
            *(float4*)(Xs + rr * 68 + k4) = xv;
        }
        // ---- stage W tile [kc x 64] at (kk, h0), coalesced float4 ----
        #pragma unroll
        for (int rep = 0; rep < 4; ++rep) {
            const int n = 4 * (rep * 256 + t);
            const int k = n >> 6;
            const int c = n & 63;
            float4 wv = make_float4(0.f, 0.f, 0.f, 0.f);
            if (k < kc && (h0 + c) < HOUT)        // HOUT%4==0, c%4==0: no quad crossing
                wv = *(const float4*)(W + (size_t)(kk + k) * HOUT + h0 + c);
            *(float4*)(Ws + n) = wv;
        }
        __syncthreads();

        const float* xp = Xs + rr * 68;
        const float* wp = Ws + 4 * cq;
        if (kc == 64) {
            #pragma unroll 16
            for (int k = 0; k < 64; ++k) {
                float x = xp[k];
                float4 wv = *(const float4*)(wp + k * 64);
                acc[0] += x * wv.x; acc[1] += x * wv.y;
                acc[2] += x * wv.z; acc[3] += x * wv.w;
            }
        } else {
            for (int k = 0; k < kc; ++k) {
                float x = xp[k];
                float4 wv = *(const float4*)(wp + k * 64);
                acc[0] += x * wv.x; acc[1] += x * wv.y;
                acc[2] += x * wv.z; acc[3] += x * wv.w;
            }
        }
        __syncthreads();
    }

    const int h = h0 + 4 * cq;
    if (h + 3 < HOUT) {                           // exact quad fit for 512 and 500
        float4 bv = *(const float4*)(bias + h);
        float4 o;
        o.x = acc[0] + bv.x; o.y = acc[1] + bv.y;
        o.z = acc[2] + bv.z; o.w = acc[3] + bv.w;
        if (RELU) {
            o.x = fmaxf(o.x, 0.f); o.y = fmaxf(o.y, 0.f);
            o.z = fmaxf(o.z, 0.f); o.w = fmaxf(o.w, 0.f);
        }
        *(float4*)(Y + (size_t)(r0 + rr) * HOUT + h) = o;
    }
}

// cvec[r,m] = -0.3 * ( (A y_x)_m + bv_m ), 4 rows per block (At reuse x4)
__global__ __launch_bounds__(256) void cvec4_kernel(const float* __restrict__ At,
                                                    const float* __restrict__ y,
                                                    const float* __restrict__ b,
                                                    float* __restrict__ cvec) {
    __shared__ float ys4[MDIM * 4];   // ys4[k*4 + r]
    const int t = threadIdx.x;
    const int row0 = blockIdx.x * 4;
    if (t < MDIM) {
        #pragma unroll
        for (int r = 0; r < 4; ++r)
            ys4[t * 4 + r] = y[(size_t)(row0 + r) * DTOT + t];
    }
    __syncthreads();
    if (t < MDIM) {
        float a0 = 0.f, a1 = 0.f, a2 = 0.f, a3 = 0.f;
        #pragma unroll 10
        for (int k = 0; k < MDIM; ++k) {
            float g = At[k * MDIM + t];           // coalesced, L2-resident
            float4 w = *(const float4*)(ys4 + 4 * k);  // uniform addr -> broadcast
            a0 += g * w.x; a1 += g * w.y; a2 += g * w.z; a3 += g * w.w;
        }
        cvec[(row0 + 0) * MDIM + t] = -0.3f * (a0 + b[(row0 + 0) * MDIM + t]);
        cvec[(row0 + 1) * MDIM + t] = -0.3f * (a1 + b[(row0 + 1) * MDIM + t]);
        cvec[(row0 + 2) * MDIM + t] = -0.3f * (a2 + b[(row0 + 2) * MDIM + t]);
        cvec[(row0 + 3) * MDIM + t] = -0.3f * (a3 + b[(row0 + 3) * MDIM + t]);
    }
}

// ---------------------------------------------------------------------------
// Phase B: persistent iteration, 256 blocks x 512 threads (8 waves/CU,
// 2 waves/SIMD for latency hiding), 4 batch rows/block.
// R6/R8-verified Q-only math; R9 delta: K-split matvec — waves 0-3 (col j=t)
// accumulate k in [0,125) from LDS, waves 4-7 (col j=t-256) accumulate
// k in [125,QC) from LDS + [QC,250) from global; partials combined via vp.
// Readlane preloads are unconditional; half-branches are wave-uniform (all 64
// lanes execute) so the R7 exec-mask hazard cannot occur.
// LDS: qc[QC*250] | w4[1024] | v4[1000] | vp[1000] | redv[32]|redw[32]|redy[8]
// UNCHANGED in R10 (Phase A round — clean attribution).
// ---------------------------------------------------------------------------
template<int QC>   // QC in (125, 160], LDS budget: QC*1000B + ~12.5 KB
__global__ __launch_bounds__(512, 1) void iterate_kernel(const float* __restrict__ Qg,
                                                         const float* __restrict__ Aaug,
                                                         const float* __restrict__ b,
                                                         const float* __restrict__ y,
                                                         const float* __restrict__ cvec,
                                                         float* __restrict__ out) {
    extern __shared__ __align__(16) float smem[];
    float* qc   = smem;                  // QC*250
    float* w4   = smem + QC * MDIM;      // 1024: w4[m*4 + row], [1000..1023] zero pad
    float* v4   = w4 + 1024;             // 1000: v4[j*4 + row]
    float* vp   = v4 + 1000;             // 1000: half-1 partial v
    float* redv = vp + 1000;             // 2 x 16
    float* redw = redv + 32;             // 2 x 16
    float* redy = redw + 32;             // 2 x 4

    const int t = threadIdx.x;
    const int row0 = blockIdx.x * 4;
    const float inv12 = 1.0f / 1.2f;
    const int r_ = t >> 6;               // wave id 0..7
    const int l  = t & 63;
    const bool h0 = (t < 256);           // wave-uniform half
    const int tt = h0 ? t : (t - 256);   // column j within half
    const int jm = (tt < MDIM) ? tt : 0; // clamped column

    // stage Q cache rows [0, QC)
    for (int e = t; e < QC * MDIM / 4; e += 512)
        ((float4*)qc)[e] = ((const float4*)Qg)[e];

    // init w = -bv (s=0), zero w4 pad; compute ||y_x||^2 per row
    float vold[4] = {0, 0, 0, 0}, wold[4] = {0, 0, 0, 0}, U[4] = {0, 0, 0, 0};
    float yx2[4] = {0, 0, 0, 0};
    if (t < MDIM) {
        #pragma unroll
        for (int r = 0; r < 4; ++r) {
            w4[t * 4 + r] = -b[(row0 + r) * MDIM + t];
            float v = y[(row0 + r) * DTOT + t];
            yx2[r] = v * v;
        }
    }
    if (t >= 256 && t < 280) w4[1000 + (t - 256)] = 0.0f;
    if (r_ < 4) {
        #pragma unroll
        for (int r = 0; r < 4; ++r) {
            float s = yx2[r];
            #pragma unroll
            for (int off = 32; off > 0; off >>= 1) s += __shfl_xor(s, off);
            if (l == 0) redv[r_ * 4 + r] = s;
        }
    }
    __syncthreads();
    float ynx[4];
    #pragma unroll
    for (int r = 0; r < 4; ++r)
        ynx[r] = sqrtf(redv[r] + redv[4 + r] + redv[8 + r] + redv[12 + r]);
    __syncthreads();

    // elementwise per-thread constants (waves 0-3 only; wave r_ owns row r_)
    float sy[4] = {0, 0, 0, 0}, yy[4] = {0, 0, 0, 0}, cv[4] = {0, 0, 0, 0};
    if (r_ < 4) {
        #pragma unroll
        for (int m = 0; m < 4; ++m) {
            int j = l + 64 * m;
            if (j < MDIM) {
                yy[m] = y[(row0 + r_) * DTOT + NDIM + j];
                cv[m] = cvec[(row0 + r_) * MDIM + j];
            }
        }
    }

    float D[4] = {0, 0, 0, 0};
    float pw = 1.0f;
    float rho = 1.0f, prev8 = 0.0f;
    bool last = false;

    for (int it = 0; ; ++it) {
        const int par = it & 1;

        // ---- unconditional lane-distributed w preloads (exec-safe) ----
        const int hbA = h0 ? 0 : 125;     // wrA covers k = hbA + lane
        const int hbB = h0 ? 64 : 189;    // wrB covers k = hbB + lane
        const float4 wrA = *(const float4*)(w4 + 4 * (hbA + l));
        const float4 wrB = *(const float4*)(w4 + 4 * (hbB + l));

        // ---- half-split partial matvec (all threads; discards for jm clamp) ----
        float a0 = 0.f, a1 = 0.f, a2 = 0.f, a3 = 0.f;
        if (h0) {
            // k in [0,125) — all from LDS
            const float* qp = qc + jm;
            #pragma unroll
            for (int k = 0; k < 125; ++k) {
                float q = qp[k * MDIM];
                const float4 ws = (k < 64) ? wrA : wrB;
                const int ln = (k < 64) ? k : (k - 64);
                a0 += q * rlane(ws.x, ln);
                a1 += q * rlane(ws.y, ln);
                a2 += q * rlane(ws.z, ln);
                a3 += q * rlane(ws.w, ln);
            }
        } else {
            // k in [125,QC) from LDS
            const float* qp = qc + 125 * MDIM + jm;
            #pragma unroll
            for (int k2 = 0; k2 < QC - 125; ++k2) {
                const int k = 125 + k2;
                float q = qp[k2 * MDIM];
                const float4 ws = (k < 189) ? wrA : wrB;
                const int ln = (k < 189) ? (k - 125) : (k - 189);
                a0 += q * rlane(ws.x, ln);
                a1 += q * rlane(ws.y, ln);
                a2 += q * rlane(ws.z, ln);
                a3 += q * rlane(ws.w, ln);
            }
            // k in [QC,250) streamed coalesced from global (L2-resident)
            const float* gp = Qg + QC * MDIM + jm;
            #pragma unroll
            for (int k2 = 0; k2 < MDIM - QC; ++k2) {
                const int k = QC + k2;
                float q = gp[k2 * MDIM];
                const float4 ws = (k < 189) ? wrA : wrB;
                const int ln = (k < 189) ? (k - 125) : (k - 189);
                a0 += q * rlane(ws.x, ln);
                a1 += q * rlane(ws.y, ln);
                a2 += q * rlane(ws.z, ln);
                a3 += q * rlane(ws.w, ln);
            }
            if (tt < MDIM) {
                float4 p = {a0, a1, a2, a3};
                *(float4*)(vp + 4 * tt) = p;
            }
        }
        __syncthreads();   // (A) vp ready

        // ---- combine + state update (half-0 threads t < 250) ----
        float dv2[4] = {0, 0, 0, 0}, dvdw[4] = {0, 0, 0, 0};
        if (t < MDIM) {
            float4 p = *(const float4*)(vp + 4 * t);
            a0 += p.x; a1 += p.y; a2 += p.z; a3 += p.w;
            float4 wcur = *(const float4*)(w4 + 4 * t);
            float d;
            d = a0 - vold[0]; dv2[0] = d * d; dvdw[0] = d * (wcur.x - wold[0]);
            d = a1 - vold[1]; dv2[1] = d * d; dvdw[1] = d * (wcur.y - wold[1]);
            d = a2 - vold[2]; dv2[2] = d * d; dvdw[2] = d * (wcur.z - wold[2]);
            d = a3 - vold[3]; dv2[3] = d * d; dvdw[3] = d * (wcur.w - wold[3]);
            wold[0] = wcur.x; wold[1] = wcur.y; wold[2] = wcur.z; wold[3] = wcur.w;
            float4 vnew = {a0, a1, a2, a3};
            *(float4*)(v4 + 4 * t) = vnew;
            vold[0] = a0; vold[1] = a1; vold[2] = a2; vold[3] = a3;
            if (!last) {
                U[0] = 0.7f * U[0] + a0; U[1] = 0.7f * U[1] + a1;
                U[2] = 0.7f * U[2] + a2; U[3] = 0.7f * U[3] + a3;
            }
        }
        if (!last && r_ < 4) {
            #pragma unroll
            for (int r = 0; r < 4; ++r) {
                float s = dv2[r], q = dvdw[r];
                #pragma unroll
                for (int off = 32; off > 0; off >>= 1) {
                    s += __shfl_xor(s, off);
                    q += __shfl_xor(q, off);
                }
                if (l == 0) { redv[par * 16 + r_ * 4 + r] = s; redw[par * 16 + r_ * 4 + r] = q; }
            }
        }
        __syncthreads();   // (B) v4 / red ready

        if (last) {
            // z_y = s_y - v  (waves 0-3 elementwise mapping)
            if (r_ < 4) {
                #pragma unroll
                for (int m = 0; m < 4; ++m) {
                    int j = l + 64 * m;
                    if (j < MDIM) out[(row0 + r_) * DTOT + NDIM + j] = sy[m] - v4[j * 4 + r_];
                }
            }
            // f = 1.2 U + v into w4
            if (t < MDIM) {
                float4 f = {1.2f * U[0] + vold[0], 1.2f * U[1] + vold[1],
                            1.2f * U[2] + vold[2], 1.2f * U[3] + vold[3]};
                *(float4*)(w4 + 4 * t) = f;
            }
            __syncthreads();
            // z_x,i = -(1-pw) y_x,i - sum_m A[m,i] f_m
            if (t < MDIM) {
                float om = 1.0f - pw;
                float z0 = -om * y[(row0 + 0) * DTOT + t];
                float z1 = -om * y[(row0 + 1) * DTOT + t];
                float z2 = -om * y[(row0 + 2) * DTOT + t];
                float z3 = -om * y[(row0 + 3) * DTOT + t];
                #pragma unroll 10
                for (int m = 0; m < MDIM; ++m) {
                    float g = Aaug[m * DTOT + t];
                    float4 f = *(const float4*)(w4 + 4 * m);
                    z0 -= g * f.x; z1 -= g * f.y; z2 -= g * f.z; z3 -= g * f.w;
                }
                out[(row0 + 0) * DTOT + t] = z0;
                out[(row0 + 1) * DTOT + t] = z1;
                out[(row0 + 2) * DTOT + t] = z2;
                out[(row0 + 3) * DTOT + t] = z3;
            }
            return;
        }

        // ---- elementwise y-part DR update + w recurrence (waves 0-3) ----
        if (r_ < 4) {
            float tpv[4], zv2[4], wv2[4], vv2[4];
            float nrm = 0.0f, tvalr = 0.0f;
            #pragma unroll
            for (int m = 0; m < 4; ++m) {
                int j = l + 64 * m;
                if (j < MDIM) {
                    float v = v4[j * 4 + r_];
                    float w = w4[j * 4 + r_];
                    float z = sy[m] - v;
                    float tp = (2.0f * z - sy[m] - 2.0f * SIGMA_C * yy[m]) * inv12;
                    tpv[m] = tp; zv2[m] = z; wv2[m] = w; vv2[m] = v;
                    if (j < MDIM - 1) nrm += tp * tp;
                    else tvalr = tp;
                } else { tpv[m] = zv2[m] = wv2[m] = vv2[m] = 0.0f; }
            }
            #pragma unroll
            for (int off = 32; off > 0; off >>= 1) nrm += __shfl_xor(nrm, off);
            float norm = sqrtf(nrm);
            float tval = __shfl(tvalr, 57);   // lane 57, m=3 holds j=249
            float fac = (tval + norm) * 0.5f / (norm + 1e-12f);
            bool keep = (norm <= tval);
            bool zero = (norm <= -tval);
            float dsy2 = 0.0f;
            #pragma unroll
            for (int m = 0; m < 4; ++m) {
                int j = l + 64 * m;
                if (j < MDIM) {
                    float tk;
                    if (j < MDIM - 1) tk = keep ? tpv[m] : (zero ? 0.0f : fac * tpv[m]);
                    else              tk = keep ? tpv[m] : (zero ? 0.0f : (tval + norm) * 0.5f);
                    float snew = sy[m] + OMEGA_C * (tk - zv2[m]);
                    float d = snew - sy[m];
                    dsy2 += d * d;
                    w4[j * 4 + r_] = -0.5f * wv2[m] + 1.2f * vv2[m] + cv[m] + (snew - 0.7f * sy[m]);
                    sy[m] = snew;
                }
            }
            #pragma unroll
            for (int off = 32; off > 0; off >>= 1) dsy2 += __shfl_xor(dsy2, off);
            if (l == 0) redy[par * 4 + r_] = dsy2;
        }
        __syncthreads();   // (C) w4 / redy ready

        // ---- uniform exit decision (all 8 waves; reads parity-buffered LDS) ----
        {
            float maxstep = 0.0f;
            #pragma unroll
            for (int r = 0; r < 4; ++r) {
                float dv2r  = redv[par * 16 + r] + redv[par * 16 + 4 + r]
                            + redv[par * 16 + 8 + r] + redv[par * 16 + 12 + r];
                float dvdwr = redw[par * 16 + r] + redw[par * 16 + 4 + r]
                            + redw[par * 16 + 8 + r] + redw[par * 16 + 12 + r];
                float atdv = sqrtf(fmaxf(dvdwr - dv2r, 0.0f));   // exact ||A^T dv||
                D[r] = (it == 0) ? (1.2f * atdv + 0.3f * ynx[r])
                                 : (0.7f * D[r] + 1.2f * atdv);
                float st = sqrtf(D[r] * D[r] + redy[par * 4 + r]);
                maxstep = fmaxf(maxstep, st);
            }
            pw *= 0.7f;
            if (it == 0) prev8 = maxstep;
            else if ((it & 7) == 0) {
                float ratio = maxstep / fmaxf(prev8, 1e-30f);
                rho = exp2f(0.125f * __log2f(fmaxf(ratio, 1e-20f)));
                prev8 = maxstep;
            }
            bool geo = (it >= 8) && (rho < 0.99f) &&
                       (1.5f * maxstep * rho / (1.0f - rho) < EXIT_BOUND);
            if (it >= N_ITER - 1 || geo ||
                (float)(N_ITER - 1 - it) * maxstep < EXIT_BOUND)
                last = true;
        }
    }
}

// ---------------------------------------------------------------------------
extern "C" void kernel_launch(void* const* d_in, const int* in_sizes, int n_in,
                              void* d_out, int out_size, void* d_ws, size_t ws_size,
                              hipStream_t stream) {
    const float* b    = (const float*)d_in[0];
    const float* c    = (const float*)d_in[1];
    const float* W1   = (const float*)d_in[2];
    const float* b1   = (const float*)d_in[3];
    const float* W2   = (const float*)d_in[4];
    const float* b2   = (const float*)d_in[5];
    const float* W3   = (const float*)d_in[6];
    const float* b3   = (const float*)d_in[7];
    const float* Aaug = (const float*)d_in[8];
    const float* Ainv = (const float*)d_in[9];
    float* out = (float*)d_out;

    const float* Qg = Ainv + MDIM * MDIM;    // bottom half of Aaug_inv = Q (250x250)

    float* ws = (float*)d_ws;
    float* At   = ws;                        // 62,500
    float* x1   = At + MDIM * MDIM;          // 1024*512
    float* x2   = x1 + BATCH * HDIM;         // 1024*512
    float* y    = x2 + BATCH * HDIM;         // 1024*500
    float* cvec = y + BATCH * DTOT;          // 1024*250

    at_kernel<<<(MDIM * MDIM + 255) / 256, 256, 0, stream>>>(Aaug, At);
    gemm_kernel<DTOT, HDIM, true,  true ><<<dim3(BATCH / 16, HDIM / 64), 256, 0, stream>>>(b, c, W1, b1, x1);
    gemm_kernel<HDIM, HDIM, true,  false><<<dim3(BATCH / 16, HDIM / 64), 256, 0, stream>>>(x1, nullptr, W2, b2, x2);
    gemm_kernel<HDIM, DTOT, false, false><<<dim3(BATCH / 16, (DTOT + 63) / 64), 256, 0, stream>>>(x2, nullptr, W3, b3, y);
    cvec4_kernel<<<BATCH / 4, 256, 0, stream>>>(At, y, b, cvec);

    constexpr int QC_BIG = 144, QC_SMALL = 128;
    size_t sh_big   = (size_t)(QC_BIG * MDIM + 3096) * sizeof(float);   // 156,384 B
    size_t sh_small = (size_t)(QC_SMALL * MDIM + 3096) * sizeof(float); // 140,384 B
    hipError_t e = hipFuncSetAttribute((const void*)iterate_kernel<QC_BIG>,
                                       hipFuncAttributeMaxDynamicSharedMemorySize,
                                       (int)sh_big);
    if (e == hipSuccess) {
        iterate_kernel<QC_BIG><<<256, 512, sh_big, stream>>>(Qg, Aaug, b, y, cvec, out);
    } else {
        hipFuncSetAttribute((const void*)iterate_kernel<QC_SMALL>,
                            hipFuncAttributeMaxDynamicSharedMemorySize, (int)sh_small);
        iterate_kernel<QC_SMALL><<<256, 512, sh_small, stream>>>(Qg, Aaug, b, y, cvec, out);
    }
}